// Round 5
// baseline (227.816 us; speedup 1.0000x reference)
//
#include <hip/hip_runtime.h>
#include <hip/hip_bf16.h>
#include <hip/hip_fp16.h>

#define HC 64          // HEADS * C
#define D_IN 128
#define NEG_SLOPE 0.2f
#define BK 64          // nodes per bucket
#define BCAP2 1536     // bucket capacity (mean 1024, 16 sigma margin)
#define NBIN 2048      // padded bucket count (actual 1563)
#define L2E 1.44269504f

using f32x4 = __attribute__((ext_vector_type(4))) float;
using f16x8 = __attribute__((ext_vector_type(8))) _Float16;
using f16x2 = __attribute__((ext_vector_type(2))) _Float16;

// ---------------- bfill[b] = b*BCAP2 ----------------
__global__ void k_iota(int* __restrict__ p, int n) {
    int i = blockIdx.x * blockDim.x + threadIdx.x;
    if (i < n) p[i] = i * BCAP2;
}

// ============ fused scat + proj (data-independent, overlap on chip) =========
// Blocks [0, nscat): R13 LDS-histogram CSR scatter (~23 us of work).
// Blocks [nscat, nscat+1024): barrier-free zero-LDS MFMA projection.
// The two roles share no data; fusing lets scat's latency-bound blocks run
// concurrently with proj's MFMA/stream blocks instead of serializing.
__global__ __launch_bounds__(256, 4) void k_projscat(
    const float* __restrict__ x,
    const float* __restrict__ Wl, const float* __restrict__ bl,
    const float* __restrict__ Wr, const float* __restrict__ br,
    __half* __restrict__ xlh, float* __restrict__ xr,
    const int* __restrict__ src, const int* __restrict__ dst, int E,
    int* __restrict__ bfill, unsigned* __restrict__ coarse, int N) {
    __shared__ int h[NBIN], sbl[NBIN], cur[NBIN];   // 24 KB (scat role only)
    const int t = threadIdx.x;
    const int nscat = (E + 4095) >> 12;             // 391

    if ((int)blockIdx.x < nscat) {
        // ---------------- scat role (R13 verbatim) ----------------
        for (int i = t; i < NBIN; i += 256) { h[i] = 0; cur[i] = 0; }
        __syncthreads();
        const int beg = blockIdx.x * 4096;
        int4 d4[4], s4[4];
#pragma unroll
        for (int r = 0; r < 4; ++r) {
            const int idx = beg + 4 * t + r * 1024;
            if (idx < E) {
                d4[r] = *(const int4*)(dst + idx);
                s4[r] = *(const int4*)(src + idx);
            } else { d4[r] = make_int4(-1, -1, -1, -1); }
        }
#pragma unroll
        for (int r = 0; r < 4; ++r) {
            if (d4[r].x >= 0) {
                atomicAdd(&h[d4[r].x >> 6], 1);
                atomicAdd(&h[d4[r].y >> 6], 1);
                atomicAdd(&h[d4[r].z >> 6], 1);
                atomicAdd(&h[d4[r].w >> 6], 1);
            }
        }
        __syncthreads();
        for (int i = t; i < NBIN; i += 256)
            sbl[i] = h[i] ? atomicAdd(&bfill[i], h[i]) : 0;
        __syncthreads();
#pragma unroll
        for (int r = 0; r < 4; ++r) {
            if (d4[r].x >= 0) {
                const int dd[4] = {d4[r].x, d4[r].y, d4[r].z, d4[r].w};
                const int ss[4] = {s4[r].x, s4[r].y, s4[r].z, s4[r].w};
#pragma unroll
                for (int j = 0; j < 4; ++j) {
                    const int bin = dd[j] >> 6;
                    const int pos = atomicAdd(&cur[bin], 1);
                    coarse[sbl[bin] + pos] = ((unsigned)ss[j] << 6) | (unsigned)(dd[j] & 63);
                }
            }
        }
        return;
    }

    // ---------------- proj role (R17 barrier-free) ----------------
    const int pb  = blockIdx.x - nscat;
    const int npb = gridDim.x - nscat;              // 1024
    const int lane = t & 63;
    const int wave = t >> 6;
    const int m = lane & 15;
    const int q = lane >> 4;

    f16x8 bf[2][4];
    float bfu[2];
#pragma unroll
    for (int cc = 0; cc < 2; ++cc) {
        const int ct = wave * 2 + cc;
        const int ch = (ct & 3) * 16 + m;
        const float* W = (ct < 4) ? Wl : Wr;
        bfu[cc] = (ct < 4) ? bl[ch] : br[ch];
#pragma unroll
        for (int kk = 0; kk < 4; ++kk) {
            const float* wp = W + (size_t)(kk * 32 + q * 8) * 64 + ch;
            f16x8 v;
#pragma unroll
            for (int e = 0; e < 8; ++e)
                v[e] = (_Float16)wp[(size_t)e * 64];
            bf[cc][kk] = v;
        }
    }

    const int ntrip = N >> 5;              // 3125 (N % 32 == 0)
    for (int trip = pb; trip < ntrip; trip += npb) {
        const int i0 = trip << 5;
        f16x8 af[2][4];
#pragma unroll
        for (int tt = 0; tt < 2; ++tt) {
            const float* xp = x + (size_t)(i0 + tt * 16 + m) * D_IN + q * 8;
#pragma unroll
            for (int kk = 0; kk < 4; ++kk) {
                const float4 f0 = *(const float4*)(xp + kk * 32);
                const float4 f1 = *(const float4*)(xp + kk * 32 + 4);
                f16x8 v;
                v[0] = (_Float16)f0.x; v[1] = (_Float16)f0.y;
                v[2] = (_Float16)f0.z; v[3] = (_Float16)f0.w;
                v[4] = (_Float16)f1.x; v[5] = (_Float16)f1.y;
                v[6] = (_Float16)f1.z; v[7] = (_Float16)f1.w;
                af[tt][kk] = v;
            }
        }
#pragma unroll
        for (int cc = 0; cc < 2; ++cc) {
            const int ct = wave * 2 + cc;
            f32x4 acc0 = {0.f, 0.f, 0.f, 0.f};
            f32x4 acc1 = {0.f, 0.f, 0.f, 0.f};
#pragma unroll
            for (int kk = 0; kk < 4; ++kk) {
                acc0 = __builtin_amdgcn_mfma_f32_16x16x32_f16(af[0][kk], bf[cc][kk], acc0, 0, 0, 0);
                acc1 = __builtin_amdgcn_mfma_f32_16x16x32_f16(af[1][kk], bf[cc][kk], acc1, 0, 0, 0);
            }
            const float bv = bfu[cc];
            if (ct < 4) {
                const int ch = ct * 16 + m;
#pragma unroll
                for (int r = 0; r < 4; ++r) {
                    xlh[(size_t)(i0 + q * 4 + r) * HC + ch]      = __float2half(acc0[r] + bv);
                    xlh[(size_t)(i0 + 16 + q * 4 + r) * HC + ch] = __float2half(acc1[r] + bv);
                }
            } else {
                const int ch = (ct - 4) * 16 + m;
#pragma unroll
                for (int r = 0; r < 4; ++r) {
                    xr[(size_t)(i0 + q * 4 + r) * HC + ch]      = acc0[r] + bv;
                    xr[(size_t)(i0 + 16 + q * 4 + r) * HC + ch] = acc1[r] + bv;
                }
            }
        }
    }
}

// ------------- fused sort + aggregation + epilogue --------------------------
// R18: two nodes (nl, nl+4) processed concurrently per wave -> 2 independent
// gather->compute chains, up to 4 outstanding 16B gathers (was 2). VGPR grows
// ~36 -> ~80; wave residency stays grid-limited (6.1 blocks/CU) so occupancy
// is unchanged while memory-level parallelism doubles.
__device__ __forceinline__ float redpair(float v) {
    int a = __builtin_amdgcn_update_dpp(0, __float_as_int(v), 0xB1, 0xF, 0xF, true);
    return v + __int_as_float(a);   // quad_perm [1,0,3,2] = xor1
}

__global__ __launch_bounds__(256) void k_aggs(
    const __half* __restrict__ xlh, const float* __restrict__ xr,
    const float* __restrict__ att, const float* __restrict__ bias,
    const float* __restrict__ Wh, const float* __restrict__ bh,
    const int* __restrict__ bfill, const unsigned* __restrict__ coarse,
    float* __restrict__ out, int N) {
    __shared__ int s_src[BCAP2];          // 6 KB
    __shared__ int s_cnt[BK], s_off[BK], s_cur[BK], s_scan[BK];
    const int t = threadIdx.x;
    const int b = blockIdx.x;
    const int eb = b * BCAP2;
    const int ee = bfill[b];              // eb + bucket edge count
    if (t < BK) { s_cnt[t] = 0; s_cur[t] = 0; }
    __syncthreads();
    // stage entries in registers (<=6 per thread), LDS histogram
    unsigned er[6]; int nr = 0;
#pragma unroll
    for (int r = 0; r < 6; ++r) {
        const int idx = eb + t + r * 256;
        if (idx < ee) er[nr++] = coarse[idx];
    }
    for (int k = 0; k < nr; ++k) atomicAdd(&s_cnt[er[k] & 63], 1);
    __syncthreads();
    if (t < BK) s_scan[t] = s_cnt[t];
    __syncthreads();
    for (int o = 1; o < BK; o <<= 1) {
        int v = (t < BK && t >= o) ? s_scan[t - o] : 0;
        __syncthreads();
        if (t < BK) s_scan[t] += v;
        __syncthreads();
    }
    if (t < BK) s_off[t] = s_scan[t] - s_cnt[t];
    __syncthreads();
    for (int k = 0; k < nr; ++k) {
        const int bin = er[k] & 63;
        const int pos = atomicAdd(&s_cur[bin], 1);
        s_src[s_off[bin] + pos] = (int)(er[k] >> 6);
    }
    __syncthreads();

    // ---- aggregation phase ----
    const int wave = t >> 6;
    const int lane = t & 63;
    const int sub  = lane & 7;      // channels 8sub..8sub+7
    const int slot = lane >> 3;     // edge slot 0..7
    const _Float16* xlhp = (const _Float16*)xlh;

    const float4 atA = *(const float4*)(att + 8 * sub);
    const float4 atB = *(const float4*)(att + 8 * sub + 4);
    f16x2 at[4];
    at[0][0] = (_Float16)(atA.x * L2E); at[0][1] = (_Float16)(atA.y * L2E);
    at[1][0] = (_Float16)(atA.z * L2E); at[1][1] = (_Float16)(atA.w * L2E);
    at[2][0] = (_Float16)(atB.x * L2E); at[2][1] = (_Float16)(atB.y * L2E);
    at[3][0] = (_Float16)(atB.z * L2E); at[3][1] = (_Float16)(atB.w * L2E);
    const f16x2 c02 = {(_Float16)NEG_SLOPE, (_Float16)NEG_SLOPE};
    const float4 biA = *(const float4*)(bias + 8 * sub);
    const float4 biB = *(const float4*)(bias + 8 * sub + 4);
    const float4 whA = *(const float4*)(Wh + 8 * sub);
    const float4 whB = *(const float4*)(Wh + 8 * sub + 4);
    const float bhv = bh[0];

#define EG_LOAD(RAW, J)                                                      \
    const uint4 RAW = *(const uint4*)(xlhp + ((size_t)(J) << 6) + 8 * sub);

#define EG_COMP(RAW, XRI, S, A, PRED)                                        \
    {                                                                        \
        f16x2 xv[4];                                                         \
        xv[0] = __builtin_bit_cast(f16x2, RAW.x);                            \
        xv[1] = __builtin_bit_cast(f16x2, RAW.y);                            \
        xv[2] = __builtin_bit_cast(f16x2, RAW.z);                            \
        xv[3] = __builtin_bit_cast(f16x2, RAW.w);                            \
        float tt = 0.f;                                                      \
        _Pragma("unroll")                                                    \
        for (int c = 0; c < 4; ++c) {                                        \
            f16x2 w = xv[c] + XRI[c];                                        \
            w = __builtin_elementwise_max(w, w * c02);                       \
            tt = __builtin_amdgcn_fdot2(at[c], w, tt, false);                \
        }                                                                    \
        tt = redpair(tt);                                                    \
        const float pe = (PRED) ? exp2f(tt) : 0.f;                           \
        S += pe;                                                             \
        _Pragma("unroll")                                                    \
        for (int c = 0; c < 4; ++c) {                                        \
            A[2 * c]     = fmaf(pe, (float)xv[c][0], A[2 * c]);              \
            A[2 * c + 1] = fmaf(pe, (float)xv[c][1], A[2 * c + 1]);          \
        }                                                                    \
    }

#define SELF_INIT(XLI, XRI, S, A)                                            \
    {                                                                        \
        float t0 = 0.f;                                                      \
        _Pragma("unroll")                                                    \
        for (int c = 0; c < 4; ++c) {                                        \
            f16x2 w = XLI[c] + XRI[c];                                       \
            w = __builtin_elementwise_max(w, w * c02);                       \
            t0 = __builtin_amdgcn_fdot2(at[c], w, t0, false);                \
        }                                                                    \
        t0 = redpair(t0);                                                    \
        const float pe0 = (slot == 0) ? exp2f(t0) : 0.f;                     \
        S = pe0;                                                             \
        _Pragma("unroll")                                                    \
        for (int c = 0; c < 4; ++c) {                                        \
            A[2 * c]     = pe0 * (float)XLI[c][0];                           \
            A[2 * c + 1] = pe0 * (float)XLI[c][1];                           \
        }                                                                    \
    }

    for (int k8 = 0; k8 < 8; ++k8) {
        const int nl0 = wave + 8 * k8;            // two nodes per iteration
        const int nl1 = nl0 + 4;
        const int i0n = (b << 6) + nl0;
        const int i1n = (b << 6) + nl1;
        const bool v0 = i0n < N;
        const bool v1 = i1n < N;
        const int is0 = v0 ? i0n : 0;
        const int is1 = v1 ? i1n : 0;
        const int beg0 = s_off[nl0];
        const int cnt0 = v0 ? s_cnt[nl0] : 0;
        const int beg1 = s_off[nl1];
        const int cnt1 = v1 ? s_cnt[nl1] : 0;

        // issue all per-node loads before converting (6 loads in flight)
        const float4 xr0a = *(const float4*)(xr + ((size_t)is0 << 6) + 8 * sub);
        const float4 xr0b = *(const float4*)(xr + ((size_t)is0 << 6) + 8 * sub + 4);
        const uint4  xl0r = *(const uint4*)(xlhp + ((size_t)is0 << 6) + 8 * sub);
        const float4 xr1a = *(const float4*)(xr + ((size_t)is1 << 6) + 8 * sub);
        const float4 xr1b = *(const float4*)(xr + ((size_t)is1 << 6) + 8 * sub + 4);
        const uint4  xl1r = *(const uint4*)(xlhp + ((size_t)is1 << 6) + 8 * sub);

        f16x2 xri0[4], xli0[4], xri1[4], xli1[4];
        xri0[0][0] = (_Float16)xr0a.x; xri0[0][1] = (_Float16)xr0a.y;
        xri0[1][0] = (_Float16)xr0a.z; xri0[1][1] = (_Float16)xr0a.w;
        xri0[2][0] = (_Float16)xr0b.x; xri0[2][1] = (_Float16)xr0b.y;
        xri0[3][0] = (_Float16)xr0b.z; xri0[3][1] = (_Float16)xr0b.w;
        xri1[0][0] = (_Float16)xr1a.x; xri1[0][1] = (_Float16)xr1a.y;
        xri1[1][0] = (_Float16)xr1a.z; xri1[1][1] = (_Float16)xr1a.w;
        xri1[2][0] = (_Float16)xr1b.x; xri1[2][1] = (_Float16)xr1b.y;
        xri1[3][0] = (_Float16)xr1b.z; xri1[3][1] = (_Float16)xr1b.w;
        xli0[0] = __builtin_bit_cast(f16x2, xl0r.x);
        xli0[1] = __builtin_bit_cast(f16x2, xl0r.y);
        xli0[2] = __builtin_bit_cast(f16x2, xl0r.z);
        xli0[3] = __builtin_bit_cast(f16x2, xl0r.w);
        xli1[0] = __builtin_bit_cast(f16x2, xl1r.x);
        xli1[1] = __builtin_bit_cast(f16x2, xl1r.y);
        xli1[2] = __builtin_bit_cast(f16x2, xl1r.z);
        xli1[3] = __builtin_bit_cast(f16x2, xl1r.w);

        float s0, s1, a0[8], a1[8];
        SELF_INIT(xli0, xri0, s0, a0)
        SELF_INIT(xli1, xri1, s1, a1)

        int p0 = 0, p1 = 0;
        // joint main loop: 2 groups per node per iter = 4 outstanding gathers
        while (p0 + 16 <= cnt0 && p1 + 16 <= cnt1) {
            const int j00 = s_src[beg0 + p0 + slot];
            const int j01 = s_src[beg0 + p0 + 8 + slot];
            const int j10 = s_src[beg1 + p1 + slot];
            const int j11 = s_src[beg1 + p1 + 8 + slot];
            EG_LOAD(r00, j00)
            EG_LOAD(r01, j01)
            EG_LOAD(r10, j10)
            EG_LOAD(r11, j11)
            EG_COMP(r00, xri0, s0, a0, true)
            EG_COMP(r01, xri0, s0, a0, true)
            EG_COMP(r10, xri1, s1, a1, true)
            EG_COMP(r11, xri1, s1, a1, true)
            p0 += 16; p1 += 16;
        }
        // joint single-group step: 2 outstanding gathers
        while (p0 + 8 <= cnt0 && p1 + 8 <= cnt1) {
            const int j00 = s_src[beg0 + p0 + slot];
            const int j10 = s_src[beg1 + p1 + slot];
            EG_LOAD(r00, j00)
            EG_LOAD(r10, j10)
            EG_COMP(r00, xri0, s0, a0, true)
            EG_COMP(r10, xri1, s1, a1, true)
            p0 += 8; p1 += 8;
        }
        // drain node0
        for (; p0 + 16 <= cnt0; p0 += 16) {
            const int ja = s_src[beg0 + p0 + slot];
            const int jb = s_src[beg0 + p0 + 8 + slot];
            EG_LOAD(ra, ja)
            EG_LOAD(rb, jb)
            EG_COMP(ra, xri0, s0, a0, true)
            EG_COMP(rb, xri0, s0, a0, true)
        }
        if (p0 + 8 <= cnt0) {
            const int ja = s_src[beg0 + p0 + slot];
            EG_LOAD(ra, ja)
            EG_COMP(ra, xri0, s0, a0, true)
            p0 += 8;
        }
        {
            const int rem = cnt0 - p0;
            if (rem > 0) {
                const int idx = p0 + slot;
                const int ja = s_src[beg0 + ((idx < cnt0) ? idx : (cnt0 - 1))];
                EG_LOAD(ra, ja)
                EG_COMP(ra, xri0, s0, a0, slot < rem)
            }
        }
        // drain node1
        for (; p1 + 16 <= cnt1; p1 += 16) {
            const int ja = s_src[beg1 + p1 + slot];
            const int jb = s_src[beg1 + p1 + 8 + slot];
            EG_LOAD(ra, ja)
            EG_LOAD(rb, jb)
            EG_COMP(ra, xri1, s1, a1, true)
            EG_COMP(rb, xri1, s1, a1, true)
        }
        if (p1 + 8 <= cnt1) {
            const int ja = s_src[beg1 + p1 + slot];
            EG_LOAD(ra, ja)
            EG_COMP(ra, xri1, s1, a1, true)
            p1 += 8;
        }
        {
            const int rem = cnt1 - p1;
            if (rem > 0) {
                const int idx = p1 + slot;
                const int ja = s_src[beg1 + ((idx < cnt1) ? idx : (cnt1 - 1))];
                EG_LOAD(ra, ja)
                EG_COMP(ra, xri1, s1, a1, slot < rem)
            }
        }

        // interleaved cross-lane reductions for both nodes
        s0 += __shfl_xor(s0, 8);  s1 += __shfl_xor(s1, 8);
        s0 += __shfl_xor(s0, 16); s1 += __shfl_xor(s1, 16);
        s0 += __shfl_xor(s0, 32); s1 += __shfl_xor(s1, 32);
#pragma unroll
        for (int c = 0; c < 8; ++c) {
            a0[c] += __shfl_xor(a0[c], 8);  a1[c] += __shfl_xor(a1[c], 8);
            a0[c] += __shfl_xor(a0[c], 16); a1[c] += __shfl_xor(a1[c], 16);
            a0[c] += __shfl_xor(a0[c], 32); a1[c] += __shfl_xor(a1[c], 32);
        }
        const float inv0 = 1.f / s0;
        const float inv1 = 1.f / s1;
        float y0 = fmaxf(a0[0] * inv0 + biA.x, 0.f) * whA.x
                 + fmaxf(a0[1] * inv0 + biA.y, 0.f) * whA.y
                 + fmaxf(a0[2] * inv0 + biA.z, 0.f) * whA.z
                 + fmaxf(a0[3] * inv0 + biA.w, 0.f) * whA.w
                 + fmaxf(a0[4] * inv0 + biB.x, 0.f) * whB.x
                 + fmaxf(a0[5] * inv0 + biB.y, 0.f) * whB.y
                 + fmaxf(a0[6] * inv0 + biB.z, 0.f) * whB.z
                 + fmaxf(a0[7] * inv0 + biB.w, 0.f) * whB.w;
        float y1 = fmaxf(a1[0] * inv1 + biA.x, 0.f) * whA.x
                 + fmaxf(a1[1] * inv1 + biA.y, 0.f) * whA.y
                 + fmaxf(a1[2] * inv1 + biA.z, 0.f) * whA.z
                 + fmaxf(a1[3] * inv1 + biA.w, 0.f) * whA.w
                 + fmaxf(a1[4] * inv1 + biB.x, 0.f) * whB.x
                 + fmaxf(a1[5] * inv1 + biB.y, 0.f) * whB.y
                 + fmaxf(a1[6] * inv1 + biB.z, 0.f) * whB.z
                 + fmaxf(a1[7] * inv1 + biB.w, 0.f) * whB.w;
        y0 += __shfl_xor(y0, 1);  y1 += __shfl_xor(y1, 1);
        y0 += __shfl_xor(y0, 2);  y1 += __shfl_xor(y1, 2);
        y0 += __shfl_xor(y0, 4);  y1 += __shfl_xor(y1, 4);
        if (lane == 0) {
            if (v0) out[i0n] = y0 + bhv;
            if (v1) out[i1n] = y1 + bhv;
        }
    }
#undef EG_LOAD
#undef EG_COMP
#undef SELF_INIT
}

// ---------------- launch ----------------
extern "C" void kernel_launch(void* const* d_in, const int* in_sizes, int n_in,
                              void* d_out, int out_size, void* d_ws, size_t ws_size,
                              hipStream_t stream) {
    const float* x   = (const float*)d_in[0];
    const int*   ei  = (const int*)d_in[1];
    const float* Wl  = (const float*)d_in[2];
    const float* bl  = (const float*)d_in[3];
    const float* Wr  = (const float*)d_in[4];
    const float* br  = (const float*)d_in[5];
    const float* att = (const float*)d_in[6];
    const float* bias= (const float*)d_in[7];
    const float* Wh  = (const float*)d_in[8];
    const float* bh  = (const float*)d_in[9];
    float* out = (float*)d_out;

    const int N = in_sizes[0] / D_IN;      // 100000
    const int E = in_sizes[1] / 2;         // 1600000
    const int* src = ei;
    const int* dst = ei + E;
    const int nbkt = (N + BK - 1) / BK;    // 1563
    const int nscat = (E + 4095) / 4096;   // 391

    // workspace layout (256B aligned)
    auto align = [](size_t v) { return (v + 255) & ~(size_t)255; };
    char* ws = (char*)d_ws;
    size_t off = 0;
    __half* xlh     = (__half*)(ws + off);   off = align(off + (size_t)N * HC * 2);
    float* xr       = (float*)(ws + off);    off = align(off + (size_t)N * HC * 4);
    int*   bfill    = (int*)(ws + off);      off = align(off + NBIN * 4);
    unsigned* coarse= (unsigned*)(ws + off); off = align(off + (size_t)NBIN * BCAP2 * 4);
    (void)ws_size;

    k_iota<<<8, 256, 0, stream>>>(bfill, NBIN);

    k_projscat<<<nscat + 1024, 256, 0, stream>>>(x, Wl, bl, Wr, br, xlh, xr,
                                                 src, dst, E, bfill, coarse, N);

    k_aggs<<<nbkt, 256, 0, stream>>>(xlh, xr, att, bias, Wh, bh,
                                     bfill, coarse, out, N);
}

// Round 6
// 209.438 us; speedup vs baseline: 1.0877x; 1.0877x over previous
//
#include <hip/hip_runtime.h>
#include <hip/hip_bf16.h>
#include <hip/hip_fp16.h>

#define HC 64          // HEADS * C
#define D_IN 128
#define NEG_SLOPE 0.2f
#define BK 64          // nodes per scat bucket
#define BKH 32         // nodes per aggs half-bucket
#define BCAP2 1536     // bucket capacity (mean 1024, 16 sigma margin)
#define NBIN 2048      // padded bucket count (actual 1563)
#define L2E 1.44269504f

using f32x4 = __attribute__((ext_vector_type(4))) float;
using f16x8 = __attribute__((ext_vector_type(8))) _Float16;
using f16x2 = __attribute__((ext_vector_type(2))) _Float16;

// ---------------- bfill[b] = b*BCAP2 ----------------
__global__ void k_iota(int* __restrict__ p, int n) {
    int i = blockIdx.x * blockDim.x + threadIdx.x;
    if (i < n) p[i] = i * BCAP2;
}

// ---------------- MFMA projection (R0/R13 LDS version, best measured) ------
__global__ __launch_bounds__(256, 3) void k_proj(
    const float* __restrict__ x,
    const float* __restrict__ Wl, const float* __restrict__ bl,
    const float* __restrict__ Wr, const float* __restrict__ br,
    __half* __restrict__ xlh, float* __restrict__ xr, int N) {
    __shared__ _Float16 sWT[128 * 136];   // 34 KB: B-frags sWT[c*136+k]
    __shared__ _Float16 sX[32 * 136];     // 8.5 KB: A rows sX[r*136+k]
    const int t = threadIdx.x;
    for (int idx = t; idx < 8192; idx += 256) {
        const int k = idx >> 6;
        const int c = idx & 63;
        sWT[c * 136 + k]        = (_Float16)Wl[idx];
        sWT[(c + 64) * 136 + k] = (_Float16)Wr[idx];
    }
    const int lane = t & 63;
    const int wave = t >> 6;
    const int m = lane & 15;
    const int q = lane >> 4;
    float bfu[2];
#pragma unroll
    for (int cc = 0; cc < 2; ++cc) {
        const int ct = wave * 2 + cc;
        const int ch = (ct & 3) * 16 + m;
        bfu[cc] = (ct < 4) ? bl[ch] : br[ch];
    }
    __syncthreads();

    const int ntrip = N >> 5;
    for (int trip = blockIdx.x; trip < ntrip; trip += gridDim.x) {
        const int i0 = trip << 5;
        for (int c = t; c < 1024; c += 256) {
            const int r = c >> 5, c4 = c & 31;
            float4 v = ((const float4*)(x + (size_t)(i0 + r) * D_IN))[c4];
            _Float16* dp = &sX[r * 136 + c4 * 4];
            dp[0] = (_Float16)v.x; dp[1] = (_Float16)v.y;
            dp[2] = (_Float16)v.z; dp[3] = (_Float16)v.w;
        }
        __syncthreads();
        f16x8 af[2][4];
#pragma unroll
        for (int tt = 0; tt < 2; ++tt)
#pragma unroll
            for (int kk = 0; kk < 4; ++kk)
                af[tt][kk] = *(const f16x8*)&sX[(tt * 16 + m) * 136 + kk * 32 + q * 8];
#pragma unroll
        for (int cc = 0; cc < 2; ++cc) {
            const int ct = wave * 2 + cc;
            const _Float16* bp = &sWT[(ct * 16 + m) * 136 + q * 8];
            f32x4 acc0 = {0.f, 0.f, 0.f, 0.f};
            f32x4 acc1 = {0.f, 0.f, 0.f, 0.f};
#pragma unroll
            for (int kk = 0; kk < 4; ++kk) {
                f16x8 bf = *(const f16x8*)(bp + kk * 32);
                acc0 = __builtin_amdgcn_mfma_f32_16x16x32_f16(af[0][kk], bf, acc0, 0, 0, 0);
                acc1 = __builtin_amdgcn_mfma_f32_16x16x32_f16(af[1][kk], bf, acc1, 0, 0, 0);
            }
            const float bv = bfu[cc];
            if (ct < 4) {
                const int ch = ct * 16 + m;
#pragma unroll
                for (int r = 0; r < 4; ++r) {
                    xlh[(size_t)(i0 + q * 4 + r) * HC + ch]      = __float2half(acc0[r] + bv);
                    xlh[(size_t)(i0 + 16 + q * 4 + r) * HC + ch] = __float2half(acc1[r] + bv);
                }
            } else {
                const int ch = (ct - 4) * 16 + m;
#pragma unroll
                for (int r = 0; r < 4; ++r) {
                    xr[(size_t)(i0 + q * 4 + r) * HC + ch]      = acc0[r] + bv;
                    xr[(size_t)(i0 + 16 + q * 4 + r) * HC + ch] = acc1[r] + bv;
                }
            }
        }
        __syncthreads();
    }
}

// ============ CSR build (R13 verbatim, ~23 us) ==============================
__global__ __launch_bounds__(256) void k_scat1(const int* __restrict__ src,
                                               const int* __restrict__ dst, int E,
                                               int* __restrict__ bfill,
                                               unsigned* __restrict__ coarse) {
    __shared__ int h[NBIN], bl[NBIN], cur[NBIN];   // 24 KB
    const int t = threadIdx.x;
    for (int i = t; i < NBIN; i += 256) { h[i] = 0; cur[i] = 0; }
    __syncthreads();
    const int beg = blockIdx.x * 4096;
    int4 d4[4], s4[4];
#pragma unroll
    for (int r = 0; r < 4; ++r) {
        const int idx = beg + 4 * t + r * 1024;
        if (idx < E) {
            d4[r] = *(const int4*)(dst + idx);
            s4[r] = *(const int4*)(src + idx);
        } else { d4[r] = make_int4(-1, -1, -1, -1); }
    }
#pragma unroll
    for (int r = 0; r < 4; ++r) {
        if (d4[r].x >= 0) {
            atomicAdd(&h[d4[r].x >> 6], 1);
            atomicAdd(&h[d4[r].y >> 6], 1);
            atomicAdd(&h[d4[r].z >> 6], 1);
            atomicAdd(&h[d4[r].w >> 6], 1);
        }
    }
    __syncthreads();
    for (int i = t; i < NBIN; i += 256)
        bl[i] = h[i] ? atomicAdd(&bfill[i], h[i]) : 0;
    __syncthreads();
#pragma unroll
    for (int r = 0; r < 4; ++r) {
        if (d4[r].x >= 0) {
            const int dd[4] = {d4[r].x, d4[r].y, d4[r].z, d4[r].w};
            const int ss[4] = {s4[r].x, s4[r].y, s4[r].z, s4[r].w};
#pragma unroll
            for (int j = 0; j < 4; ++j) {
                const int bin = dd[j] >> 6;
                const int pos = atomicAdd(&cur[bin], 1);
                coarse[bl[bin] + pos] = ((unsigned)ss[j] << 6) | (unsigned)(dd[j] & 63);
            }
        }
    }
}

// ------------- fused sort + aggregation + epilogue --------------------------
// R19: (a) each 64-node bucket split across TWO blocks (payload bit5 selects
// half) -> 3126 blocks = 12.2/CU -> 32 waves/CU residency (was 24.4), halved
// per-wave serial work, finer load balance. (b) accumulation uses
// v_dot2_f32_f16 with {peh,0}/{0,peh} instead of 8 cvt + 8 fma (f32 acc
// kept; s summed from same peh -> consistent softmax). (c) xor-8 reduction
// step via DPP row_ror:8 instead of ds_swizzle.
__device__ __forceinline__ float redpair(float v) {
    int a = __builtin_amdgcn_update_dpp(0, __float_as_int(v), 0xB1, 0xF, 0xF, true);
    return v + __int_as_float(a);   // quad_perm [1,0,3,2] = xor1
}
__device__ __forceinline__ float red8(float v) {
    int a = __builtin_amdgcn_update_dpp(0, __float_as_int(v), 0x128, 0xF, 0xF, true);
    return v + __int_as_float(a);   // row_ror:8 = lane^8 within 16-lane row
}

__global__ __launch_bounds__(256) void k_aggs(
    const __half* __restrict__ xlh, const float* __restrict__ xr,
    const float* __restrict__ att, const float* __restrict__ bias,
    const float* __restrict__ Wh, const float* __restrict__ bh,
    const int* __restrict__ bfill, const unsigned* __restrict__ coarse,
    float* __restrict__ out, int N) {
    __shared__ int s_src[BCAP2];          // 6 KB
    __shared__ int s_cnt[BKH], s_off[BKH], s_cur[BKH], s_scan[BKH];
    const int t = threadIdx.x;
    const int bkt = blockIdx.x >> 1;
    const int half = blockIdx.x & 1;
    const int eb = bkt * BCAP2;
    const int ee = bfill[bkt];            // eb + bucket edge count
    if (t < BKH) { s_cnt[t] = 0; s_cur[t] = 0; }
    __syncthreads();
    // stage this half's entries in registers (<=6 per thread), LDS histogram
    unsigned er[6]; int nr = 0;
#pragma unroll
    for (int r = 0; r < 6; ++r) {
        const int idx = eb + t + r * 256;
        if (idx < ee) {
            const unsigned e = coarse[idx];
            if (((e >> 5) & 1u) == (unsigned)half) er[nr++] = e;
        }
    }
    for (int k = 0; k < nr; ++k) atomicAdd(&s_cnt[er[k] & 31], 1);
    __syncthreads();
    if (t < BKH) s_scan[t] = s_cnt[t];
    __syncthreads();
    for (int o = 1; o < BKH; o <<= 1) {
        int v = (t < BKH && t >= o) ? s_scan[t - o] : 0;
        __syncthreads();
        if (t < BKH) s_scan[t] += v;
        __syncthreads();
    }
    if (t < BKH) s_off[t] = s_scan[t] - s_cnt[t];
    __syncthreads();
    for (int k = 0; k < nr; ++k) {
        const int bin = er[k] & 31;
        const int pos = atomicAdd(&s_cur[bin], 1);
        s_src[s_off[bin] + pos] = (int)(er[k] >> 6);
    }
    __syncthreads();

    // ---- aggregation phase ----
    const int wave = t >> 6;
    const int lane = t & 63;
    const int sub  = lane & 7;      // channels 8sub..8sub+7
    const int slot = lane >> 3;     // edge slot 0..7
    const _Float16* xlhp = (const _Float16*)xlh;

    const float4 atA = *(const float4*)(att + 8 * sub);
    const float4 atB = *(const float4*)(att + 8 * sub + 4);
    f16x2 at[4];
    at[0][0] = (_Float16)(atA.x * L2E); at[0][1] = (_Float16)(atA.y * L2E);
    at[1][0] = (_Float16)(atA.z * L2E); at[1][1] = (_Float16)(atA.w * L2E);
    at[2][0] = (_Float16)(atB.x * L2E); at[2][1] = (_Float16)(atB.y * L2E);
    at[3][0] = (_Float16)(atB.z * L2E); at[3][1] = (_Float16)(atB.w * L2E);
    const f16x2 c02 = {(_Float16)NEG_SLOPE, (_Float16)NEG_SLOPE};
    const _Float16 h0 = (_Float16)0.f;
    const float4 biA = *(const float4*)(bias + 8 * sub);
    const float4 biB = *(const float4*)(bias + 8 * sub + 4);
    const float4 whA = *(const float4*)(Wh + 8 * sub);
    const float4 whB = *(const float4*)(Wh + 8 * sub + 4);
    const float bhv = bh[0];

    for (int k8 = 0; k8 < 8; ++k8) {
        const int nl = wave + 4 * k8;             // 0..31, interleaved
        const int i = bkt * 64 + half * 32 + nl;
        if (i >= N) continue;
        const int beg = s_off[nl];
        const int cnt = s_cnt[nl];

        const float4 xrA = *(const float4*)(xr + ((size_t)i << 6) + 8 * sub);
        const float4 xrB = *(const float4*)(xr + ((size_t)i << 6) + 8 * sub + 4);
        f16x2 xri[4];
        xri[0][0] = (_Float16)xrA.x; xri[0][1] = (_Float16)xrA.y;
        xri[1][0] = (_Float16)xrA.z; xri[1][1] = (_Float16)xrA.w;
        xri[2][0] = (_Float16)xrB.x; xri[2][1] = (_Float16)xrB.y;
        xri[3][0] = (_Float16)xrB.z; xri[3][1] = (_Float16)xrB.w;
        const uint4 xliraw = *(const uint4*)(xlhp + ((size_t)i << 6) + 8 * sub);
        f16x2 xli[4];
        xli[0] = __builtin_bit_cast(f16x2, xliraw.x);
        xli[1] = __builtin_bit_cast(f16x2, xliraw.y);
        xli[2] = __builtin_bit_cast(f16x2, xliraw.z);
        xli[3] = __builtin_bit_cast(f16x2, xliraw.w);

        float t0 = 0.f;
#pragma unroll
        for (int c = 0; c < 4; ++c) {
            f16x2 w = xli[c] + xri[c];
            w = __builtin_elementwise_max(w, w * c02);
            t0 = __builtin_amdgcn_fdot2(at[c], w, t0, false);
        }
        t0 = redpair(t0);
        const _Float16 pe0h = (slot == 0) ? (_Float16)exp2f(t0) : h0;
        const f16x2 p0A = {pe0h, h0};
        const f16x2 p0B = {h0, pe0h};
        float s = (float)pe0h;
        float a[8];
#pragma unroll
        for (int c = 0; c < 4; ++c) {
            a[2 * c]     = __builtin_amdgcn_fdot2(xli[c], p0A, 0.f, false);
            a[2 * c + 1] = __builtin_amdgcn_fdot2(xli[c], p0B, 0.f, false);
        }

        int p = 0;
#define EDGE_GROUP(JEXPR, PRED)                                              \
    {                                                                        \
        const int jj = (JEXPR);                                              \
        const uint4 raw = *(const uint4*)(xlhp + ((size_t)jj << 6) + 8 * sub);\
        f16x2 xv[4];                                                         \
        xv[0] = __builtin_bit_cast(f16x2, raw.x);                            \
        xv[1] = __builtin_bit_cast(f16x2, raw.y);                            \
        xv[2] = __builtin_bit_cast(f16x2, raw.z);                            \
        xv[3] = __builtin_bit_cast(f16x2, raw.w);                            \
        float tt = 0.f;                                                      \
        _Pragma("unroll")                                                    \
        for (int c = 0; c < 4; ++c) {                                        \
            f16x2 w = xv[c] + xri[c];                                        \
            w = __builtin_elementwise_max(w, w * c02);                       \
            tt = __builtin_amdgcn_fdot2(at[c], w, tt, false);                \
        }                                                                    \
        tt = redpair(tt);                                                    \
        const _Float16 peh = (PRED) ? (_Float16)exp2f(tt) : h0;              \
        const f16x2 pA = {peh, h0};                                          \
        const f16x2 pB = {h0, peh};                                          \
        s += (float)peh;                                                     \
        _Pragma("unroll")                                                    \
        for (int c = 0; c < 4; ++c) {                                        \
            a[2 * c]     = __builtin_amdgcn_fdot2(xv[c], pA, a[2 * c], false);\
            a[2 * c + 1] = __builtin_amdgcn_fdot2(xv[c], pB, a[2 * c + 1], false);\
        }                                                                    \
    }
        for (; p + 16 <= cnt; p += 16) {
            const int j0 = s_src[beg + p + slot];
            const int j1 = s_src[beg + p + 8 + slot];
            EDGE_GROUP(j0, true)
            EDGE_GROUP(j1, true)
        }
        if (p + 8 <= cnt) {
            const int j0 = s_src[beg + p + slot];
            EDGE_GROUP(j0, true)
            p += 8;
        }
        const int rem = cnt - p;
        if (rem > 0) {
            const int idx = p + slot;
            const int j0 = s_src[beg + ((idx < cnt) ? idx : (cnt - 1))];
            EDGE_GROUP(j0, slot < rem)
        }
#undef EDGE_GROUP

        s = red8(s);  s += __shfl_xor(s, 16);  s += __shfl_xor(s, 32);
#pragma unroll
        for (int c = 0; c < 8; ++c) {
            a[c] = red8(a[c]);
            a[c] += __shfl_xor(a[c], 16);
            a[c] += __shfl_xor(a[c], 32);
        }
        const float inv = 1.f / s;
        float y = fmaxf(a[0] * inv + biA.x, 0.f) * whA.x
                + fmaxf(a[1] * inv + biA.y, 0.f) * whA.y
                + fmaxf(a[2] * inv + biA.z, 0.f) * whA.z
                + fmaxf(a[3] * inv + biA.w, 0.f) * whA.w
                + fmaxf(a[4] * inv + biB.x, 0.f) * whB.x
                + fmaxf(a[5] * inv + biB.y, 0.f) * whB.y
                + fmaxf(a[6] * inv + biB.z, 0.f) * whB.z
                + fmaxf(a[7] * inv + biB.w, 0.f) * whB.w;
        y += __shfl_xor(y, 1);
        y += __shfl_xor(y, 2);
        y += __shfl_xor(y, 4);
        if (lane == 0) out[i] = y + bhv;
    }
}

// ---------------- launch ----------------
extern "C" void kernel_launch(void* const* d_in, const int* in_sizes, int n_in,
                              void* d_out, int out_size, void* d_ws, size_t ws_size,
                              hipStream_t stream) {
    const float* x   = (const float*)d_in[0];
    const int*   ei  = (const int*)d_in[1];
    const float* Wl  = (const float*)d_in[2];
    const float* bl  = (const float*)d_in[3];
    const float* Wr  = (const float*)d_in[4];
    const float* br  = (const float*)d_in[5];
    const float* att = (const float*)d_in[6];
    const float* bias= (const float*)d_in[7];
    const float* Wh  = (const float*)d_in[8];
    const float* bh  = (const float*)d_in[9];
    float* out = (float*)d_out;

    const int N = in_sizes[0] / D_IN;      // 100000
    const int E = in_sizes[1] / 2;         // 1600000
    const int* src = ei;
    const int* dst = ei + E;
    const int nbkt = (N + BK - 1) / BK;    // 1563

    // workspace layout (256B aligned)
    auto align = [](size_t v) { return (v + 255) & ~(size_t)255; };
    char* ws = (char*)d_ws;
    size_t off = 0;
    __half* xlh     = (__half*)(ws + off);   off = align(off + (size_t)N * HC * 2);
    float* xr       = (float*)(ws + off);    off = align(off + (size_t)N * HC * 4);
    int*   bfill    = (int*)(ws + off);      off = align(off + NBIN * 4);
    unsigned* coarse= (unsigned*)(ws + off); off = align(off + (size_t)NBIN * BCAP2 * 4);
    (void)ws_size;

    k_iota<<<8, 256, 0, stream>>>(bfill, NBIN);

    k_proj<<<1024, 256, 0, stream>>>(x, Wl, bl, Wr, br, xlh, xr, N);

    k_scat1<<<(E + 4095) / 4096, 256, 0, stream>>>(src, dst, E, bfill, coarse);

    k_aggs<<<nbkt * 2, 256, 0, stream>>>(xlh, xr, att, bias, Wh, bh,
                                         bfill, coarse, out, N);
}

// Round 7
// 208.183 us; speedup vs baseline: 1.0943x; 1.0060x over previous
//
#include <hip/hip_runtime.h>
#include <hip/hip_bf16.h>
#include <hip/hip_fp16.h>

#define HC 64          // HEADS * C
#define D_IN 128
#define NEG_SLOPE 0.2f
#define BK 64          // nodes per scat bucket
#define BKQ 16         // nodes per aggs quarter-bucket
#define BCAP2 1536     // bucket capacity (mean 1024, 16 sigma margin)
#define NBIN 2048      // padded bucket count (actual 1563)
#define L2E 1.44269504f

using f32x4 = __attribute__((ext_vector_type(4))) float;
using f16x8 = __attribute__((ext_vector_type(8))) _Float16;
using f16x2 = __attribute__((ext_vector_type(2))) _Float16;

// ---------------- bfill[b] = b*BCAP2 ----------------
__global__ void k_iota(int* __restrict__ p, int n) {
    int i = blockIdx.x * blockDim.x + threadIdx.x;
    if (i < n) p[i] = i * BCAP2;
}

// ---------------- MFMA projection (R0/R13 LDS version, best measured) ------
__global__ __launch_bounds__(256, 3) void k_proj(
    const float* __restrict__ x,
    const float* __restrict__ Wl, const float* __restrict__ bl,
    const float* __restrict__ Wr, const float* __restrict__ br,
    __half* __restrict__ xlh, float* __restrict__ xr, int N) {
    __shared__ _Float16 sWT[128 * 136];   // 34 KB: B-frags sWT[c*136+k]
    __shared__ _Float16 sX[32 * 136];     // 8.5 KB: A rows sX[r*136+k]
    const int t = threadIdx.x;
    for (int idx = t; idx < 8192; idx += 256) {
        const int k = idx >> 6;
        const int c = idx & 63;
        sWT[c * 136 + k]        = (_Float16)Wl[idx];
        sWT[(c + 64) * 136 + k] = (_Float16)Wr[idx];
    }
    const int lane = t & 63;
    const int wave = t >> 6;
    const int m = lane & 15;
    const int q = lane >> 4;
    float bfu[2];
#pragma unroll
    for (int cc = 0; cc < 2; ++cc) {
        const int ct = wave * 2 + cc;
        const int ch = (ct & 3) * 16 + m;
        bfu[cc] = (ct < 4) ? bl[ch] : br[ch];
    }
    __syncthreads();

    const int ntrip = N >> 5;
    for (int trip = blockIdx.x; trip < ntrip; trip += gridDim.x) {
        const int i0 = trip << 5;
        for (int c = t; c < 1024; c += 256) {
            const int r = c >> 5, c4 = c & 31;
            float4 v = ((const float4*)(x + (size_t)(i0 + r) * D_IN))[c4];
            _Float16* dp = &sX[r * 136 + c4 * 4];
            dp[0] = (_Float16)v.x; dp[1] = (_Float16)v.y;
            dp[2] = (_Float16)v.z; dp[3] = (_Float16)v.w;
        }
        __syncthreads();
        f16x8 af[2][4];
#pragma unroll
        for (int tt = 0; tt < 2; ++tt)
#pragma unroll
            for (int kk = 0; kk < 4; ++kk)
                af[tt][kk] = *(const f16x8*)&sX[(tt * 16 + m) * 136 + kk * 32 + q * 8];
#pragma unroll
        for (int cc = 0; cc < 2; ++cc) {
            const int ct = wave * 2 + cc;
            const _Float16* bp = &sWT[(ct * 16 + m) * 136 + q * 8];
            f32x4 acc0 = {0.f, 0.f, 0.f, 0.f};
            f32x4 acc1 = {0.f, 0.f, 0.f, 0.f};
#pragma unroll
            for (int kk = 0; kk < 4; ++kk) {
                f16x8 bf = *(const f16x8*)(bp + kk * 32);
                acc0 = __builtin_amdgcn_mfma_f32_16x16x32_f16(af[0][kk], bf, acc0, 0, 0, 0);
                acc1 = __builtin_amdgcn_mfma_f32_16x16x32_f16(af[1][kk], bf, acc1, 0, 0, 0);
            }
            const float bv = bfu[cc];
            if (ct < 4) {
                const int ch = ct * 16 + m;
#pragma unroll
                for (int r = 0; r < 4; ++r) {
                    xlh[(size_t)(i0 + q * 4 + r) * HC + ch]      = __float2half(acc0[r] + bv);
                    xlh[(size_t)(i0 + 16 + q * 4 + r) * HC + ch] = __float2half(acc1[r] + bv);
                }
            } else {
                const int ch = (ct - 4) * 16 + m;
#pragma unroll
                for (int r = 0; r < 4; ++r) {
                    xr[(size_t)(i0 + q * 4 + r) * HC + ch]      = acc0[r] + bv;
                    xr[(size_t)(i0 + 16 + q * 4 + r) * HC + ch] = acc1[r] + bv;
                }
            }
        }
        __syncthreads();
    }
}

// ============ CSR build (R13 verbatim, ~23 us) ==============================
__global__ __launch_bounds__(256) void k_scat1(const int* __restrict__ src,
                                               const int* __restrict__ dst, int E,
                                               int* __restrict__ bfill,
                                               unsigned* __restrict__ coarse) {
    __shared__ int h[NBIN], bl[NBIN], cur[NBIN];   // 24 KB
    const int t = threadIdx.x;
    for (int i = t; i < NBIN; i += 256) { h[i] = 0; cur[i] = 0; }
    __syncthreads();
    const int beg = blockIdx.x * 4096;
    int4 d4[4], s4[4];
#pragma unroll
    for (int r = 0; r < 4; ++r) {
        const int idx = beg + 4 * t + r * 1024;
        if (idx < E) {
            d4[r] = *(const int4*)(dst + idx);
            s4[r] = *(const int4*)(src + idx);
        } else { d4[r] = make_int4(-1, -1, -1, -1); }
    }
#pragma unroll
    for (int r = 0; r < 4; ++r) {
        if (d4[r].x >= 0) {
            atomicAdd(&h[d4[r].x >> 6], 1);
            atomicAdd(&h[d4[r].y >> 6], 1);
            atomicAdd(&h[d4[r].z >> 6], 1);
            atomicAdd(&h[d4[r].w >> 6], 1);
        }
    }
    __syncthreads();
    for (int i = t; i < NBIN; i += 256)
        bl[i] = h[i] ? atomicAdd(&bfill[i], h[i]) : 0;
    __syncthreads();
#pragma unroll
    for (int r = 0; r < 4; ++r) {
        if (d4[r].x >= 0) {
            const int dd[4] = {d4[r].x, d4[r].y, d4[r].z, d4[r].w};
            const int ss[4] = {s4[r].x, s4[r].y, s4[r].z, s4[r].w};
#pragma unroll
            for (int j = 0; j < 4; ++j) {
                const int bin = dd[j] >> 6;
                const int pos = atomicAdd(&cur[bin], 1);
                coarse[bl[bin] + pos] = ((unsigned)ss[j] << 6) | (unsigned)(dd[j] & 63);
            }
        }
    }
}

// ------------- fused sort + aggregation + epilogue --------------------------
// R20: quarter-bucket split (16 nodes/block, payload bits 4-5 select quarter)
// -> 6252 blocks = 25K waves = 3.05 residency rounds (was 1.53) -> smaller
// tail, finer load balance, per-wave serial work halved again. Coarse range
// re-read 4x (mostly L2/LLC-absorbed). Rest identical to R19 (dot2 accum,
// DPP reductions, VGPR 32).
__device__ __forceinline__ float redpair(float v) {
    int a = __builtin_amdgcn_update_dpp(0, __float_as_int(v), 0xB1, 0xF, 0xF, true);
    return v + __int_as_float(a);   // quad_perm [1,0,3,2] = xor1
}
__device__ __forceinline__ float red8(float v) {
    int a = __builtin_amdgcn_update_dpp(0, __float_as_int(v), 0x128, 0xF, 0xF, true);
    return v + __int_as_float(a);   // row_ror:8 = lane^8 within 16-lane row
}

__global__ __launch_bounds__(256) void k_aggs(
    const __half* __restrict__ xlh, const float* __restrict__ xr,
    const float* __restrict__ att, const float* __restrict__ bias,
    const float* __restrict__ Wh, const float* __restrict__ bh,
    const int* __restrict__ bfill, const unsigned* __restrict__ coarse,
    float* __restrict__ out, int N) {
    __shared__ int s_src[BCAP2];          // 6 KB (worst-case skew safe)
    __shared__ int s_cnt[BKQ], s_off[BKQ], s_cur[BKQ], s_scan[BKQ];
    const int t = threadIdx.x;
    const int bkt  = blockIdx.x >> 2;
    const int quad = blockIdx.x & 3;
    const int eb = bkt * BCAP2;
    const int ee = bfill[bkt];            // eb + bucket edge count
    if (t < BKQ) { s_cnt[t] = 0; s_cur[t] = 0; }
    __syncthreads();
    // stage this quarter's entries in registers (<=6 per thread)
    unsigned er[6]; int nr = 0;
#pragma unroll
    for (int r = 0; r < 6; ++r) {
        const int idx = eb + t + r * 256;
        if (idx < ee) {
            const unsigned e = coarse[idx];
            if (((e >> 4) & 3u) == (unsigned)quad) er[nr++] = e;
        }
    }
    for (int k = 0; k < nr; ++k) atomicAdd(&s_cnt[er[k] & 15], 1);
    __syncthreads();
    if (t < BKQ) s_scan[t] = s_cnt[t];
    __syncthreads();
    for (int o = 1; o < BKQ; o <<= 1) {
        int v = (t < BKQ && t >= o) ? s_scan[t - o] : 0;
        __syncthreads();
        if (t < BKQ) s_scan[t] += v;
        __syncthreads();
    }
    if (t < BKQ) s_off[t] = s_scan[t] - s_cnt[t];
    __syncthreads();
    for (int k = 0; k < nr; ++k) {
        const int bin = er[k] & 15;
        const int pos = atomicAdd(&s_cur[bin], 1);
        s_src[s_off[bin] + pos] = (int)(er[k] >> 6);
    }
    __syncthreads();

    // ---- aggregation phase ----
    const int wave = t >> 6;
    const int lane = t & 63;
    const int sub  = lane & 7;      // channels 8sub..8sub+7
    const int slot = lane >> 3;     // edge slot 0..7
    const _Float16* xlhp = (const _Float16*)xlh;

    const float4 atA = *(const float4*)(att + 8 * sub);
    const float4 atB = *(const float4*)(att + 8 * sub + 4);
    f16x2 at[4];
    at[0][0] = (_Float16)(atA.x * L2E); at[0][1] = (_Float16)(atA.y * L2E);
    at[1][0] = (_Float16)(atA.z * L2E); at[1][1] = (_Float16)(atA.w * L2E);
    at[2][0] = (_Float16)(atB.x * L2E); at[2][1] = (_Float16)(atB.y * L2E);
    at[3][0] = (_Float16)(atB.z * L2E); at[3][1] = (_Float16)(atB.w * L2E);
    const f16x2 c02 = {(_Float16)NEG_SLOPE, (_Float16)NEG_SLOPE};
    const _Float16 h0 = (_Float16)0.f;
    const float4 biA = *(const float4*)(bias + 8 * sub);
    const float4 biB = *(const float4*)(bias + 8 * sub + 4);
    const float4 whA = *(const float4*)(Wh + 8 * sub);
    const float4 whB = *(const float4*)(Wh + 8 * sub + 4);
    const float bhv = bh[0];

    for (int k4 = 0; k4 < 4; ++k4) {
        const int nl = wave + 4 * k4;             // 0..15, interleaved
        const int i = bkt * 64 + quad * 16 + nl;
        if (i >= N) continue;
        const int beg = s_off[nl];
        const int cnt = s_cnt[nl];

        const float4 xrA = *(const float4*)(xr + ((size_t)i << 6) + 8 * sub);
        const float4 xrB = *(const float4*)(xr + ((size_t)i << 6) + 8 * sub + 4);
        f16x2 xri[4];
        xri[0][0] = (_Float16)xrA.x; xri[0][1] = (_Float16)xrA.y;
        xri[1][0] = (_Float16)xrA.z; xri[1][1] = (_Float16)xrA.w;
        xri[2][0] = (_Float16)xrB.x; xri[2][1] = (_Float16)xrB.y;
        xri[3][0] = (_Float16)xrB.z; xri[3][1] = (_Float16)xrB.w;
        const uint4 xliraw = *(const uint4*)(xlhp + ((size_t)i << 6) + 8 * sub);
        f16x2 xli[4];
        xli[0] = __builtin_bit_cast(f16x2, xliraw.x);
        xli[1] = __builtin_bit_cast(f16x2, xliraw.y);
        xli[2] = __builtin_bit_cast(f16x2, xliraw.z);
        xli[3] = __builtin_bit_cast(f16x2, xliraw.w);

        float t0 = 0.f;
#pragma unroll
        for (int c = 0; c < 4; ++c) {
            f16x2 w = xli[c] + xri[c];
            w = __builtin_elementwise_max(w, w * c02);
            t0 = __builtin_amdgcn_fdot2(at[c], w, t0, false);
        }
        t0 = redpair(t0);
        const _Float16 pe0h = (slot == 0) ? (_Float16)exp2f(t0) : h0;
        const f16x2 p0A = {pe0h, h0};
        const f16x2 p0B = {h0, pe0h};
        float s = (float)pe0h;
        float a[8];
#pragma unroll
        for (int c = 0; c < 4; ++c) {
            a[2 * c]     = __builtin_amdgcn_fdot2(xli[c], p0A, 0.f, false);
            a[2 * c + 1] = __builtin_amdgcn_fdot2(xli[c], p0B, 0.f, false);
        }

        int p = 0;
#define EDGE_GROUP(JEXPR, PRED)                                              \
    {                                                                        \
        const int jj = (JEXPR);                                              \
        const uint4 raw = *(const uint4*)(xlhp + ((size_t)jj << 6) + 8 * sub);\
        f16x2 xv[4];                                                         \
        xv[0] = __builtin_bit_cast(f16x2, raw.x);                            \
        xv[1] = __builtin_bit_cast(f16x2, raw.y);                            \
        xv[2] = __builtin_bit_cast(f16x2, raw.z);                            \
        xv[3] = __builtin_bit_cast(f16x2, raw.w);                            \
        float tt = 0.f;                                                      \
        _Pragma("unroll")                                                    \
        for (int c = 0; c < 4; ++c) {                                        \
            f16x2 w = xv[c] + xri[c];                                        \
            w = __builtin_elementwise_max(w, w * c02);                       \
            tt = __builtin_amdgcn_fdot2(at[c], w, tt, false);                \
        }                                                                    \
        tt = redpair(tt);                                                    \
        const _Float16 peh = (PRED) ? (_Float16)exp2f(tt) : h0;              \
        const f16x2 pA = {peh, h0};                                          \
        const f16x2 pB = {h0, peh};                                          \
        s += (float)peh;                                                     \
        _Pragma("unroll")                                                    \
        for (int c = 0; c < 4; ++c) {                                        \
            a[2 * c]     = __builtin_amdgcn_fdot2(xv[c], pA, a[2 * c], false);\
            a[2 * c + 1] = __builtin_amdgcn_fdot2(xv[c], pB, a[2 * c + 1], false);\
        }                                                                    \
    }
        for (; p + 16 <= cnt; p += 16) {
            const int j0 = s_src[beg + p + slot];
            const int j1 = s_src[beg + p + 8 + slot];
            EDGE_GROUP(j0, true)
            EDGE_GROUP(j1, true)
        }
        if (p + 8 <= cnt) {
            const int j0 = s_src[beg + p + slot];
            EDGE_GROUP(j0, true)
            p += 8;
        }
        const int rem = cnt - p;
        if (rem > 0) {
            const int idx = p + slot;
            const int j0 = s_src[beg + ((idx < cnt) ? idx : (cnt - 1))];
            EDGE_GROUP(j0, slot < rem)
        }
#undef EDGE_GROUP

        s = red8(s);  s += __shfl_xor(s, 16);  s += __shfl_xor(s, 32);
#pragma unroll
        for (int c = 0; c < 8; ++c) {
            a[c] = red8(a[c]);
            a[c] += __shfl_xor(a[c], 16);
            a[c] += __shfl_xor(a[c], 32);
        }
        const float inv = 1.f / s;
        float y = fmaxf(a[0] * inv + biA.x, 0.f) * whA.x
                + fmaxf(a[1] * inv + biA.y, 0.f) * whA.y
                + fmaxf(a[2] * inv + biA.z, 0.f) * whA.z
                + fmaxf(a[3] * inv + biA.w, 0.f) * whA.w
                + fmaxf(a[4] * inv + biB.x, 0.f) * whB.x
                + fmaxf(a[5] * inv + biB.y, 0.f) * whB.y
                + fmaxf(a[6] * inv + biB.z, 0.f) * whB.z
                + fmaxf(a[7] * inv + biB.w, 0.f) * whB.w;
        y += __shfl_xor(y, 1);
        y += __shfl_xor(y, 2);
        y += __shfl_xor(y, 4);
        if (lane == 0) out[i] = y + bhv;
    }
}

// ---------------- launch ----------------
extern "C" void kernel_launch(void* const* d_in, const int* in_sizes, int n_in,
                              void* d_out, int out_size, void* d_ws, size_t ws_size,
                              hipStream_t stream) {
    const float* x   = (const float*)d_in[0];
    const int*   ei  = (const int*)d_in[1];
    const float* Wl  = (const float*)d_in[2];
    const float* bl  = (const float*)d_in[3];
    const float* Wr  = (const float*)d_in[4];
    const float* br  = (const float*)d_in[5];
    const float* att = (const float*)d_in[6];
    const float* bias= (const float*)d_in[7];
    const float* Wh  = (const float*)d_in[8];
    const float* bh  = (const float*)d_in[9];
    float* out = (float*)d_out;

    const int N = in_sizes[0] / D_IN;      // 100000
    const int E = in_sizes[1] / 2;         // 1600000
    const int* src = ei;
    const int* dst = ei + E;
    const int nbkt = (N + BK - 1) / BK;    // 1563

    // workspace layout (256B aligned)
    auto align = [](size_t v) { return (v + 255) & ~(size_t)255; };
    char* ws = (char*)d_ws;
    size_t off = 0;
    __half* xlh     = (__half*)(ws + off);   off = align(off + (size_t)N * HC * 2);
    float* xr       = (float*)(ws + off);    off = align(off + (size_t)N * HC * 4);
    int*   bfill    = (int*)(ws + off);      off = align(off + NBIN * 4);
    unsigned* coarse= (unsigned*)(ws + off); off = align(off + (size_t)NBIN * BCAP2 * 4);
    (void)ws_size;

    k_iota<<<8, 256, 0, stream>>>(bfill, NBIN);

    k_proj<<<1024, 256, 0, stream>>>(x, Wl, bl, Wr, br, xlh, xr, N);

    k_scat1<<<(E + 4095) / 4096, 256, 0, stream>>>(src, dst, E, bfill, coarse);

    k_aggs<<<nbkt * 4, 256, 0, stream>>>(xlh, xr, att, bias, Wh, bh,
                                         bfill, coarse, out, N);
}